// Round 2
// baseline (365.055 us; speedup 1.0000x reference)
//
#include <hip/hip_runtime.h>
#include <cstdint>
#include <cstddef>

#define H_DIM 1024
#define HEADS 16
#define HD 64
#define BATCH 4
#define SEQ 2048
#define M_ROWS (BATCH*SEQ)   // 8192

typedef __bf16 bf16x8 __attribute__((ext_vector_type(8)));
typedef float floatx4 __attribute__((ext_vector_type(4)));
typedef unsigned short ushortx8 __attribute__((ext_vector_type(8)));

__device__ __forceinline__ unsigned short f2bf(float f) {
    union { float f; uint32_t u; } c; c.f = f;
    uint32_t u = c.u;
    u += 0x7fffu + ((u >> 16) & 1u);     // RNE
    return (unsigned short)(u >> 16);
}
__device__ __forceinline__ float bf2f(unsigned short h) {
    union { uint32_t u; float f; } c; c.u = ((uint32_t)h) << 16;
    return c.f;
}

// async global->LDS, 16B per lane; LDS dest = wave-uniform base + lane*16 (m104/m108)
#define GLD_LDS16(gp, lp) \
    __builtin_amdgcn_global_load_lds((__attribute__((address_space(1))) void*)(gp), \
                                     (__attribute__((address_space(3))) void*)(lp), 16, 0, 0)

// ---------------- prep: 4 weight casts (z<4) + proj_b (z==4) in one launch ----
// grid (2048, 1, 5). z<4: blocks >=512 exit immediately.
__global__ __launch_bounds__(256) void prep(const float* __restrict__ Wq,
                                            const float* __restrict__ Wk,
                                            const float* __restrict__ Wv,
                                            const float* __restrict__ Wo,
                                            unsigned short* __restrict__ Wq_bf,
                                            unsigned short* __restrict__ Wk_bf,
                                            unsigned short* __restrict__ Wv_bf,
                                            unsigned short* __restrict__ Wo_bf,
                                            const float* __restrict__ beta,
                                            const float* __restrict__ Wb,
                                            const float* __restrict__ bbias,
                                            float* __restrict__ bout)
{
    const int z = blockIdx.z;
    if (z < 4) {
        if (blockIdx.x >= 512) return;
        const float* in = (z == 0) ? Wq : (z == 1) ? Wk : (z == 2) ? Wv : Wo;
        unsigned short* out = (z == 0) ? Wq_bf : (z == 1) ? Wk_bf : (z == 2) ? Wv_bf : Wo_bf;
        size_t i = (size_t)blockIdx.x * 256 + threadIdx.x;
        const float4* p = (const float4*)in;
        float4 a = p[i * 2], b = p[i * 2 + 1];
        ushortx8 o;
        o[0] = f2bf(a.x); o[1] = f2bf(a.y); o[2] = f2bf(a.z); o[3] = f2bf(a.w);
        o[4] = f2bf(b.x); o[5] = f2bf(b.y); o[6] = f2bf(b.z); o[7] = f2bf(b.w);
        *(ushortx8*)(out + i * 8) = o;
        return;
    }

    // ---- proj_b: b = sigmoid(beta @ Wb^T + bb), wave-per-row, coalesced ----
    const int wave = threadIdx.x >> 6;
    const int lane = threadIdx.x & 63;
    const int m = blockIdx.x * 4 + wave;

    const float4* brow = (const float4*)(beta + (size_t)m * H_DIM);   // 256 float4
    const float4* wb4  = (const float4*)Wb;                            // [16][256] float4

    float acc[16];
    #pragma unroll
    for (int n = 0; n < 16; ++n) acc[n] = 0.f;

    #pragma unroll
    for (int j = 0; j < 4; ++j) {
        float4 a = brow[j * 64 + lane];            // 1KB coalesced
        #pragma unroll
        for (int n = 0; n < 16; ++n) {
            float4 w = wb4[n * 256 + j * 64 + lane];   // 1KB coalesced, L1/L2-hot
            acc[n] = fmaf(a.x, w.x, acc[n]);
            acc[n] = fmaf(a.y, w.y, acc[n]);
            acc[n] = fmaf(a.z, w.z, acc[n]);
            acc[n] = fmaf(a.w, w.w, acc[n]);
        }
    }

    #pragma unroll
    for (int n = 0; n < 16; ++n) {
        float s = acc[n];
        s += __shfl_xor(s, 32);
        s += __shfl_xor(s, 16);
        s += __shfl_xor(s, 8);
        s += __shfl_xor(s, 4);
        s += __shfl_xor(s, 2);
        s += __shfl_xor(s, 1);
        acc[n] = s;
    }

    float sel = acc[0];
    #pragma unroll
    for (int n = 1; n < 16; ++n)
        sel = (lane == n) ? acc[n] : sel;
    if (lane < 16) {
        float s = sel + bbias[lane];
        bout[(size_t)m * HEADS + lane] = 1.f / (1.f + __expf(-s));
    }
}

// ---------------- fused QKV GEMM: f32 A cast to bf16 during staging ----------
// 1-D grid 1536, panel-per-XCD swizzle: each A-panel's 8 N-blocks land on one
// XCD (lin%8 = XCD), so the f32 A-panel is L2-fetched ~once per XCD instead of
// being scattered round-robin. Kills the separate activation-cast kernel.
__global__ __launch_bounds__(256) void gemm_qkv(const float* __restrict__ Aq,
                                                const float* __restrict__ Ak,
                                                const float* __restrict__ Av,
                                                const unsigned short* __restrict__ Wqb,
                                                const unsigned short* __restrict__ Wkb,
                                                const unsigned short* __restrict__ Wvb,
                                                const float* __restrict__ bq,
                                                const float* __restrict__ bk,
                                                const float* __restrict__ bv,
                                                unsigned short* __restrict__ Cq,
                                                unsigned short* __restrict__ Ck,
                                                unsigned short* __restrict__ Cv)
{
    constexpr int TM = 128, TN = 128, TK = 32;
    constexpr int K = H_DIM, N = H_DIM;
    __shared__ __align__(16) unsigned short Ast[TM * TK];
    __shared__ __align__(16) unsigned short Bst[TN * TK];

    // swizzle decode: lin -> (z, my, nx); panels = 64 M-tiles x 3 z = 192
    const int lin   = blockIdx.x;          // 0..1535
    const int xcd   = lin & 7;
    const int ii    = lin >> 3;            // 0..191 (per-XCD index)
    const int panel = xcd * 24 + (ii >> 3);
    const int nx    = ii & 7;
    const int z     = panel >> 6;          // 0..2
    const int my    = panel & 63;

    const float* A          = (z == 0) ? Aq : (z == 1) ? Ak : Av;
    const unsigned short* W = (z == 0) ? Wqb : (z == 1) ? Wkb : Wvb;
    const float* bias       = (z == 0) ? bq : (z == 1) ? bk : bv;
    unsigned short* C       = (z == 0) ? Cq : (z == 1) ? Ck : Cv;
    const bool phi = (z < 2);

    const int tid  = threadIdx.x;
    const int wave = tid >> 6;
    const int lane = tid & 63;
    const int bm = my * TM;
    const int bn = nx * TN;

    const int srow  = wave * 16 + (lane >> 2);
    const int skoff = (lane & 3) * 8;

    const int wm   = (wave & 1) * 64;
    const int wn   = (wave >> 1) * 64;
    const int quad = lane >> 4;
    const int l16  = lane & 15;

    floatx4 acc[4][4] = {};

    const float*          Abase = A + (size_t)bm * K;
    const unsigned short* Wbase = W + (size_t)bn * K;

    for (int k0 = 0; k0 < K; k0 += TK) {
        __syncthreads();
        // B: async global->LDS (bf16 weights, pre-cast)
        GLD_LDS16(Wbase + (size_t)srow        * K + k0 + skoff, &Bst[(wave * 16)      * TK]);
        GLD_LDS16(Wbase + (size_t)(srow + 64) * K + k0 + skoff, &Bst[(64 + wave * 16) * TK]);
        // A: f32 -> regs -> bf16 -> LDS (cast fused into staging)
        float4 a0 = *(const float4*)&Abase[(size_t)srow        * K + k0 + skoff];
        float4 a1 = *(const float4*)&Abase[(size_t)srow        * K + k0 + skoff + 4];
        float4 a2 = *(const float4*)&Abase[(size_t)(srow + 64) * K + k0 + skoff];
        float4 a3 = *(const float4*)&Abase[(size_t)(srow + 64) * K + k0 + skoff + 4];
        ushortx8 w0, w1;
        w0[0] = f2bf(a0.x); w0[1] = f2bf(a0.y); w0[2] = f2bf(a0.z); w0[3] = f2bf(a0.w);
        w0[4] = f2bf(a1.x); w0[5] = f2bf(a1.y); w0[6] = f2bf(a1.z); w0[7] = f2bf(a1.w);
        w1[0] = f2bf(a2.x); w1[1] = f2bf(a2.y); w1[2] = f2bf(a2.z); w1[3] = f2bf(a2.w);
        w1[4] = f2bf(a3.x); w1[5] = f2bf(a3.y); w1[6] = f2bf(a3.z); w1[7] = f2bf(a3.w);
        *(ushortx8*)&Ast[(size_t)srow        * TK + skoff] = w0;
        *(ushortx8*)&Ast[(size_t)(srow + 64) * TK + skoff] = w1;
        __syncthreads();

        bf16x8 af[4], bfr[4];
        #pragma unroll
        for (int i = 0; i < 4; ++i)
            af[i] = *(const bf16x8*)&Ast[(wm + i * 16 + l16) * TK + quad * 8];
        #pragma unroll
        for (int j = 0; j < 4; ++j)
            bfr[j] = *(const bf16x8*)&Bst[(wn + j * 16 + l16) * TK + quad * 8];
        #pragma unroll
        for (int i = 0; i < 4; ++i)
            #pragma unroll
            for (int j = 0; j < 4; ++j)
                acc[i][j] = __builtin_amdgcn_mfma_f32_16x16x32_bf16(af[i], bfr[j], acc[i][j], 0, 0, 0);
    }

    #pragma unroll
    for (int i = 0; i < 4; ++i) {
        #pragma unroll
        for (int j = 0; j < 4; ++j) {
            const int col = bn + wn + j * 16 + l16;
            const float bval = bias[col];
            #pragma unroll
            for (int r = 0; r < 4; ++r) {
                const int row = bm + wm + i * 16 + quad * 4 + r;
                float x = acc[i][j][r] + bval;
                if (phi) x = (x > 0.f) ? (x + 1.f) : __expf(x);  // elu(x)+1
                C[(size_t)row * N + col] = f2bf(x);
            }
        }
    }
}

// ---------------- output GEMM: 128x64 tile -> 1024 blocks = 4/CU -------------
// 1-D grid with same panel-per-XCD swizzle (16 N-blocks per A-panel per XCD).
__global__ __launch_bounds__(256) void gemm_out(const unsigned short* __restrict__ A,
                                                const unsigned short* __restrict__ W,
                                                const float* __restrict__ bias,
                                                float* __restrict__ C)
{
    constexpr int TM = 128, TN = 64, TK = 32;
    constexpr int K = H_DIM, N = H_DIM;
    __shared__ __align__(16) unsigned short Ast[TM * TK];
    __shared__ __align__(16) unsigned short Bst[TN * TK];

    const int lin = blockIdx.x;           // 0..1023
    const int xcd = lin & 7;
    const int ii  = lin >> 3;             // 0..127
    const int my  = xcd * 8 + (ii >> 4);  // 0..63
    const int nx  = ii & 15;              // 0..15

    const int tid  = threadIdx.x;
    const int wave = tid >> 6;
    const int lane = tid & 63;
    const int bm = my * TM;
    const int bn = nx * TN;

    const int srow  = wave * 16 + (lane >> 2);
    const int skoff = (lane & 3) * 8;

    const int wm   = (wave & 1) * 64;
    const int wn   = (wave >> 1) * 32;
    const int quad = lane >> 4;
    const int l16  = lane & 15;

    floatx4 acc[4][2] = {};

    const unsigned short* Abase = A + (size_t)bm * K;
    const unsigned short* Wbase = W + (size_t)bn * K;

    for (int k0 = 0; k0 < K; k0 += TK) {
        __syncthreads();
        GLD_LDS16(Abase + (size_t)srow        * K + k0 + skoff, &Ast[(wave * 16)      * TK]);
        GLD_LDS16(Abase + (size_t)(srow + 64) * K + k0 + skoff, &Ast[(64 + wave * 16) * TK]);
        GLD_LDS16(Wbase + (size_t)srow        * K + k0 + skoff, &Bst[(wave * 16)      * TK]);
        __syncthreads();

        bf16x8 af[4], bfr[2];
        #pragma unroll
        for (int i = 0; i < 4; ++i)
            af[i] = *(const bf16x8*)&Ast[(wm + i * 16 + l16) * TK + quad * 8];
        #pragma unroll
        for (int j = 0; j < 2; ++j)
            bfr[j] = *(const bf16x8*)&Bst[(wn + j * 16 + l16) * TK + quad * 8];
        #pragma unroll
        for (int i = 0; i < 4; ++i)
            #pragma unroll
            for (int j = 0; j < 2; ++j)
                acc[i][j] = __builtin_amdgcn_mfma_f32_16x16x32_bf16(af[i], bfr[j], acc[i][j], 0, 0, 0);
    }

    #pragma unroll
    for (int i = 0; i < 4; ++i) {
        #pragma unroll
        for (int j = 0; j < 2; ++j) {
            const int col = bn + wn + j * 16 + l16;
            const float bval = bias[col];
            #pragma unroll
            for (int r = 0; r < 4; ++r) {
                const int row = bm + wm + i * 16 + quad * 4 + r;
                C[(size_t)row * N + col] = acc[i][j][r] + bval;
            }
        }
    }
}

// ---------------- chunked parallel linear scan -------------------------------
// s_t = a_t*s_{t-1} + c_t with a = 1 - b*pk^2, c = b*v*pk.
constexpr int NCHUNK = 64;
constexpr int CLEN   = SEQ / NCHUNK;     // 32
constexpr int NGH    = BATCH * HEADS * HD;  // 4096 independent lanes

__global__ __launch_bounds__(256) void scan_phase1(const unsigned short* __restrict__ pk_,
                                                   const unsigned short* __restrict__ v_,
                                                   const float* __restrict__ b_,
                                                   float* __restrict__ Aarr,
                                                   float* __restrict__ Carr)
{
    const int idx   = blockIdx.x * 256 + threadIdx.x;   // 0 .. NGH*NCHUNK-1
    const int d     = idx & 63;
    const int h     = (idx >> 6) & 15;
    const int bb    = (idx >> 10) & 3;
    const int chunk = idx >> 12;
    const int g     = idx & (NGH - 1);
    const int t0    = chunk * CLEN;

    const unsigned short* pkp = pk_ + (size_t)bb * SEQ * H_DIM + h * HD + d + (size_t)t0 * H_DIM;
    const unsigned short* vp  = v_  + (size_t)bb * SEQ * H_DIM + h * HD + d + (size_t)t0 * H_DIM;
    const float*          bp  = b_  + (size_t)bb * SEQ * HEADS + h        + (size_t)t0 * HEADS;

    float A = 1.f, C = 0.f;
    #pragma unroll 8
    for (int t = 0; t < CLEN; ++t) {
        float pk = bf2f(pkp[(size_t)t * H_DIM]);
        float vv = bf2f(vp[(size_t)t * H_DIM]);
        float bt = bp[(size_t)t * HEADS];
        float a  = 1.f - bt * pk * pk;
        float c  = bt * vv * pk;
        A *= a;
        C = fmaf(a, C, c);
    }
    Aarr[(size_t)chunk * NGH + g] = A;
    Carr[(size_t)chunk * NGH + g] = C;
}

__global__ __launch_bounds__(256) void scan_phase2(const float* __restrict__ Aarr,
                                                   const float* __restrict__ Carr,
                                                   float* __restrict__ S0)
{
    const int g = blockIdx.x * 256 + threadIdx.x;   // 0..4095
    float s = 0.f;
    #pragma unroll
    for (int c = 0; c < NCHUNK; ++c) {
        S0[(size_t)c * NGH + g] = s;
        s = fmaf(Aarr[(size_t)c * NGH + g], s, Carr[(size_t)c * NGH + g]);
    }
}

__global__ __launch_bounds__(256) void scan_phase3(const unsigned short* __restrict__ pk_,
                                                   unsigned short* __restrict__ pq_,   // in: phi_q, out: ys
                                                   const unsigned short* __restrict__ v_,
                                                   const float* __restrict__ b_,
                                                   const float* __restrict__ S0)
{
    const int idx   = blockIdx.x * 256 + threadIdx.x;
    const int d     = idx & 63;
    const int h     = (idx >> 6) & 15;
    const int bb    = (idx >> 10) & 3;
    const int chunk = idx >> 12;
    const int g     = idx & (NGH - 1);
    const int t0    = chunk * CLEN;

    const unsigned short* pkp = pk_ + (size_t)bb * SEQ * H_DIM + h * HD + d + (size_t)t0 * H_DIM;
    unsigned short*       pqp = pq_ + (size_t)bb * SEQ * H_DIM + h * HD + d + (size_t)t0 * H_DIM;
    const unsigned short* vp  = v_  + (size_t)bb * SEQ * H_DIM + h * HD + d + (size_t)t0 * H_DIM;
    const float*          bp  = b_  + (size_t)bb * SEQ * HEADS + h        + (size_t)t0 * HEADS;

    float s = S0[(size_t)chunk * NGH + g];
    #pragma unroll 8
    for (int t = 0; t < CLEN; ++t) {
        float pk = bf2f(pkp[(size_t)t * H_DIM]);
        float pq = bf2f(pqp[(size_t)t * H_DIM]);
        float vv = bf2f(vp[(size_t)t * H_DIM]);
        float bt = bp[(size_t)t * HEADS];
        float bdv = bt * (vv - s * pk);   // identical op order to the sequential version
        s = fmaf(bdv, pk, s);
        pqp[(size_t)t * H_DIM] = f2bf(s * pq);
    }
}

extern "C" void kernel_launch(void* const* d_in, const int* in_sizes, int n_in,
                              void* d_out, int out_size, void* d_ws, size_t ws_size,
                              hipStream_t stream)
{
    const float* query = (const float*)d_in[0];
    const float* key   = (const float*)d_in[1];
    const float* value = (const float*)d_in[2];
    const float* beta  = (const float*)d_in[3];
    const float* Wq    = (const float*)d_in[4];
    const float* bq    = (const float*)d_in[5];
    const float* Wk    = (const float*)d_in[6];
    const float* bk    = (const float*)d_in[7];
    const float* Wv    = (const float*)d_in[8];
    const float* bv    = (const float*)d_in[9];
    const float* Wb    = (const float*)d_in[10];
    const float* bbias = (const float*)d_in[11];
    const float* Wo    = (const float*)d_in[12];
    const float* bo    = (const float*)d_in[13];
    float* out = (float*)d_out;

    const size_t ACT = (size_t)M_ROWS * H_DIM;   // 8 Mi elems
    const size_t WEL = (size_t)H_DIM * H_DIM;    // 1 Mi elems

    unsigned short* ws = (unsigned short*)d_ws;
    unsigned short* phi_q  = ws;                 // bf16 [8192,1024]; ys written in-place
    unsigned short* phi_k  = ws + ACT;
    unsigned short* vbuf   = ws + 2 * ACT;
    unsigned short* Wq_bf  = ws + 3 * ACT;
    unsigned short* Wk_bf  = Wq_bf + WEL;
    unsigned short* Wv_bf  = Wk_bf + WEL;
    unsigned short* Wo_bf  = Wv_bf + WEL;
    float*          bbuf   = (float*)(Wo_bf + WEL);        // [8192,16]
    float*          Aarr   = bbuf + (size_t)M_ROWS * HEADS; // [64][4096]
    float*          Carr   = Aarr + (size_t)NCHUNK * NGH;
    float*          S0     = Carr + (size_t)NCHUNK * NGH;

    // 1) weight casts + proj_b in one launch
    prep<<<dim3(2048, 1, 5), 256, 0, stream>>>(Wq, Wk, Wv, Wo,
                                               Wq_bf, Wk_bf, Wv_bf, Wo_bf,
                                               beta, Wb, bbias, bbuf);

    // 2) fused-cast QKV projections, panel-per-XCD swizzled 1-D grid
    gemm_qkv<<<1536, 256, 0, stream>>>(query, key, value,
                                       Wq_bf, Wk_bf, Wv_bf,
                                       bq, bk, bv,
                                       phi_q, phi_k, vbuf);

    // 3-5) chunked scan
    const int SCAN_BLOCKS = NGH * NCHUNK / 256;   // 1024
    scan_phase1<<<SCAN_BLOCKS, 256, 0, stream>>>(phi_k, vbuf, bbuf, Aarr, Carr);
    scan_phase2<<<NGH / 256, 256, 0, stream>>>(Aarr, Carr, S0);
    scan_phase3<<<SCAN_BLOCKS, 256, 0, stream>>>(phi_k, phi_q, vbuf, bbuf, S0);

    // 6) output projection, 128x64 tile -> 1024 blocks (4/CU), XCD-swizzled
    gemm_out<<<1024, 256, 0, stream>>>(phi_q, Wo_bf, bo, out);
}

// Round 3
// 337.779 us; speedup vs baseline: 1.0808x; 1.0808x over previous
//
#include <hip/hip_runtime.h>
#include <cstdint>
#include <cstddef>

#define H_DIM 1024
#define HEADS 16
#define HD 64
#define BATCH 4
#define SEQ 2048
#define M_ROWS (BATCH*SEQ)   // 8192

typedef __bf16 bf16x8 __attribute__((ext_vector_type(8)));
typedef float floatx4 __attribute__((ext_vector_type(4)));
typedef unsigned short ushortx8 __attribute__((ext_vector_type(8)));

__device__ __forceinline__ unsigned short f2bf(float f) {
    union { float f; uint32_t u; } c; c.f = f;
    uint32_t u = c.u;
    u += 0x7fffu + ((u >> 16) & 1u);     // RNE
    return (unsigned short)(u >> 16);
}
__device__ __forceinline__ float bf2f(unsigned short h) {
    union { uint32_t u; float f; } c; c.u = ((uint32_t)h) << 16;
    return c.f;
}

// async global->LDS, 16B per lane; LDS dest = wave-uniform base + lane*16 (m104/m108)
#define GLD_LDS16(gp, lp) \
    __builtin_amdgcn_global_load_lds((__attribute__((address_space(1))) void*)(gp), \
                                     (__attribute__((address_space(3))) void*)(lp), 16, 0, 0)

// ---------------- prep: 4 weight casts (z<4) + proj_b (z==4) in one launch ----
// grid (2048, 1, 5). z<4: blocks >=512 exit immediately.
__global__ __launch_bounds__(256) void prep(const float* __restrict__ Wq,
                                            const float* __restrict__ Wk,
                                            const float* __restrict__ Wv,
                                            const float* __restrict__ Wo,
                                            unsigned short* __restrict__ Wq_bf,
                                            unsigned short* __restrict__ Wk_bf,
                                            unsigned short* __restrict__ Wv_bf,
                                            unsigned short* __restrict__ Wo_bf,
                                            const float* __restrict__ beta,
                                            const float* __restrict__ Wb,
                                            const float* __restrict__ bbias,
                                            float* __restrict__ bout)
{
    const int z = blockIdx.z;
    if (z < 4) {
        if (blockIdx.x >= 512) return;
        const float* in = (z == 0) ? Wq : (z == 1) ? Wk : (z == 2) ? Wv : Wo;
        unsigned short* out = (z == 0) ? Wq_bf : (z == 1) ? Wk_bf : (z == 2) ? Wv_bf : Wo_bf;
        size_t i = (size_t)blockIdx.x * 256 + threadIdx.x;
        const float4* p = (const float4*)in;
        float4 a = p[i * 2], b = p[i * 2 + 1];
        ushortx8 o;
        o[0] = f2bf(a.x); o[1] = f2bf(a.y); o[2] = f2bf(a.z); o[3] = f2bf(a.w);
        o[4] = f2bf(b.x); o[5] = f2bf(b.y); o[6] = f2bf(b.z); o[7] = f2bf(b.w);
        *(ushortx8*)(out + i * 8) = o;
        return;
    }

    // ---- proj_b: b = sigmoid(beta @ Wb^T + bb), wave-per-row, coalesced ----
    const int wave = threadIdx.x >> 6;
    const int lane = threadIdx.x & 63;
    const int m = blockIdx.x * 4 + wave;

    const float4* brow = (const float4*)(beta + (size_t)m * H_DIM);   // 256 float4
    const float4* wb4  = (const float4*)Wb;                            // [16][256] float4

    float acc[16];
    #pragma unroll
    for (int n = 0; n < 16; ++n) acc[n] = 0.f;

    #pragma unroll
    for (int j = 0; j < 4; ++j) {
        float4 a = brow[j * 64 + lane];            // 1KB coalesced
        #pragma unroll
        for (int n = 0; n < 16; ++n) {
            float4 w = wb4[n * 256 + j * 64 + lane];   // 1KB coalesced, L1/L2-hot
            acc[n] = fmaf(a.x, w.x, acc[n]);
            acc[n] = fmaf(a.y, w.y, acc[n]);
            acc[n] = fmaf(a.z, w.z, acc[n]);
            acc[n] = fmaf(a.w, w.w, acc[n]);
        }
    }

    #pragma unroll
    for (int n = 0; n < 16; ++n) {
        float s = acc[n];
        s += __shfl_xor(s, 32);
        s += __shfl_xor(s, 16);
        s += __shfl_xor(s, 8);
        s += __shfl_xor(s, 4);
        s += __shfl_xor(s, 2);
        s += __shfl_xor(s, 1);
        acc[n] = s;
    }

    float sel = acc[0];
    #pragma unroll
    for (int n = 1; n < 16; ++n)
        sel = (lane == n) ? acc[n] : sel;
    if (lane < 16) {
        float s = sel + bbias[lane];
        bout[(size_t)m * HEADS + lane] = 1.f / (1.f + __expf(-s));
    }
}

// ---------------- z-batched activation f32 -> bf16 cast (8 elems/thread) -----
__global__ __launch_bounds__(256) void cast_bf16_z(const float* __restrict__ p0,
                                                   const float* __restrict__ p1,
                                                   const float* __restrict__ p2,
                                                   unsigned short* __restrict__ o0,
                                                   unsigned short* __restrict__ o1,
                                                   unsigned short* __restrict__ o2)
{
    const int z = blockIdx.z;
    const float* in = (z == 0) ? p0 : (z == 1) ? p1 : p2;
    unsigned short* out = (z == 0) ? o0 : (z == 1) ? o1 : o2;

    size_t i = (size_t)blockIdx.x * 256 + threadIdx.x;
    const float4* p = (const float4*)in;
    float4 a = p[i * 2], b = p[i * 2 + 1];
    ushortx8 o;
    o[0] = f2bf(a.x); o[1] = f2bf(a.y); o[2] = f2bf(a.z); o[3] = f2bf(a.w);
    o[4] = f2bf(b.x); o[5] = f2bf(b.y); o[6] = f2bf(b.z); o[7] = f2bf(b.w);
    *(ushortx8*)(out + i * 8) = o;
}

// ---------------- QKV GEMM: bf16 A via global_load_lds (r1 body), ------------
// 1-D grid 1536 with panel-per-XCD swizzle (r2 decode): each A-panel's 8
// N-blocks land on one XCD -> A-panel L2-fetched ~once (fetch 200->68 MB, r2).
__global__ __launch_bounds__(256) void gemm_qkv(const unsigned short* __restrict__ Aq,
                                                const unsigned short* __restrict__ Ak,
                                                const unsigned short* __restrict__ Av,
                                                const unsigned short* __restrict__ Wqb,
                                                const unsigned short* __restrict__ Wkb,
                                                const unsigned short* __restrict__ Wvb,
                                                const float* __restrict__ bq,
                                                const float* __restrict__ bk,
                                                const float* __restrict__ bv,
                                                unsigned short* __restrict__ Cq,
                                                unsigned short* __restrict__ Ck,
                                                unsigned short* __restrict__ Cv)
{
    constexpr int TM = 128, TN = 128, TK = 32;
    constexpr int K = H_DIM, N = H_DIM;
    __shared__ __align__(16) unsigned short Ast[TM * TK];
    __shared__ __align__(16) unsigned short Bst[TN * TK];

    // swizzle decode: lin -> (z, my, nx); panels = 64 M-tiles x 3 z = 192
    const int lin   = blockIdx.x;          // 0..1535
    const int xcd   = lin & 7;
    const int ii    = lin >> 3;            // 0..191 (per-XCD index)
    const int panel = xcd * 24 + (ii >> 3);
    const int nx    = ii & 7;
    const int z     = panel >> 6;          // 0..2
    const int my    = panel & 63;

    const unsigned short* A = (z == 0) ? Aq : (z == 1) ? Ak : Av;
    const unsigned short* W = (z == 0) ? Wqb : (z == 1) ? Wkb : Wvb;
    const float* bias       = (z == 0) ? bq : (z == 1) ? bk : bv;
    unsigned short* C       = (z == 0) ? Cq : (z == 1) ? Ck : Cv;
    const bool phi = (z < 2);

    const int tid  = threadIdx.x;
    const int wave = tid >> 6;
    const int lane = tid & 63;
    const int bm = my * TM;
    const int bn = nx * TN;

    const int srow  = wave * 16 + (lane >> 2);
    const int skoff = (lane & 3) * 8;

    const int wm   = (wave & 1) * 64;
    const int wn   = (wave >> 1) * 64;
    const int quad = lane >> 4;
    const int l16  = lane & 15;

    floatx4 acc[4][4] = {};

    const unsigned short* Abase = A + (size_t)bm * K;
    const unsigned short* Wbase = W + (size_t)bn * K;

    for (int k0 = 0; k0 < K; k0 += TK) {
        __syncthreads();
        GLD_LDS16(Abase + (size_t)srow        * K + k0 + skoff, &Ast[(wave * 16)      * TK]);
        GLD_LDS16(Abase + (size_t)(srow + 64) * K + k0 + skoff, &Ast[(64 + wave * 16) * TK]);
        GLD_LDS16(Wbase + (size_t)srow        * K + k0 + skoff, &Bst[(wave * 16)      * TK]);
        GLD_LDS16(Wbase + (size_t)(srow + 64) * K + k0 + skoff, &Bst[(64 + wave * 16) * TK]);
        __syncthreads();

        bf16x8 af[4], bfr[4];
        #pragma unroll
        for (int i = 0; i < 4; ++i)
            af[i] = *(const bf16x8*)&Ast[(wm + i * 16 + l16) * TK + quad * 8];
        #pragma unroll
        for (int j = 0; j < 4; ++j)
            bfr[j] = *(const bf16x8*)&Bst[(wn + j * 16 + l16) * TK + quad * 8];
        #pragma unroll
        for (int i = 0; i < 4; ++i)
            #pragma unroll
            for (int j = 0; j < 4; ++j)
                acc[i][j] = __builtin_amdgcn_mfma_f32_16x16x32_bf16(af[i], bfr[j], acc[i][j], 0, 0, 0);
    }

    #pragma unroll
    for (int i = 0; i < 4; ++i) {
        #pragma unroll
        for (int j = 0; j < 4; ++j) {
            const int col = bn + wn + j * 16 + l16;
            const float bval = bias[col];
            #pragma unroll
            for (int r = 0; r < 4; ++r) {
                const int row = bm + wm + i * 16 + quad * 4 + r;
                float x = acc[i][j][r] + bval;
                if (phi) x = (x > 0.f) ? (x + 1.f) : __expf(x);  // elu(x)+1
                C[(size_t)row * N + col] = f2bf(x);
            }
        }
    }
}

// ---------------- output GEMM: 128x64 tile -> 1024 blocks = 4/CU -------------
// 1-D grid with same panel-per-XCD swizzle (16 N-blocks per A-panel per XCD).
__global__ __launch_bounds__(256) void gemm_out(const unsigned short* __restrict__ A,
                                                const unsigned short* __restrict__ W,
                                                const float* __restrict__ bias,
                                                float* __restrict__ C)
{
    constexpr int TM = 128, TN = 64, TK = 32;
    constexpr int K = H_DIM, N = H_DIM;
    __shared__ __align__(16) unsigned short Ast[TM * TK];
    __shared__ __align__(16) unsigned short Bst[TN * TK];

    const int lin = blockIdx.x;           // 0..1023
    const int xcd = lin & 7;
    const int ii  = lin >> 3;             // 0..127
    const int my  = xcd * 8 + (ii >> 4);  // 0..63
    const int nx  = ii & 15;              // 0..15

    const int tid  = threadIdx.x;
    const int wave = tid >> 6;
    const int lane = tid & 63;
    const int bm = my * TM;
    const int bn = nx * TN;

    const int srow  = wave * 16 + (lane >> 2);
    const int skoff = (lane & 3) * 8;

    const int wm   = (wave & 1) * 64;
    const int wn   = (wave >> 1) * 32;
    const int quad = lane >> 4;
    const int l16  = lane & 15;

    floatx4 acc[4][2] = {};

    const unsigned short* Abase = A + (size_t)bm * K;
    const unsigned short* Wbase = W + (size_t)bn * K;

    for (int k0 = 0; k0 < K; k0 += TK) {
        __syncthreads();
        GLD_LDS16(Abase + (size_t)srow        * K + k0 + skoff, &Ast[(wave * 16)      * TK]);
        GLD_LDS16(Abase + (size_t)(srow + 64) * K + k0 + skoff, &Ast[(64 + wave * 16) * TK]);
        GLD_LDS16(Wbase + (size_t)srow        * K + k0 + skoff, &Bst[(wave * 16)      * TK]);
        __syncthreads();

        bf16x8 af[4], bfr[2];
        #pragma unroll
        for (int i = 0; i < 4; ++i)
            af[i] = *(const bf16x8*)&Ast[(wm + i * 16 + l16) * TK + quad * 8];
        #pragma unroll
        for (int j = 0; j < 2; ++j)
            bfr[j] = *(const bf16x8*)&Bst[(wn + j * 16 + l16) * TK + quad * 8];
        #pragma unroll
        for (int i = 0; i < 4; ++i)
            #pragma unroll
            for (int j = 0; j < 2; ++j)
                acc[i][j] = __builtin_amdgcn_mfma_f32_16x16x32_bf16(af[i], bfr[j], acc[i][j], 0, 0, 0);
    }

    #pragma unroll
    for (int i = 0; i < 4; ++i) {
        #pragma unroll
        for (int j = 0; j < 2; ++j) {
            const int col = bn + wn + j * 16 + l16;
            const float bval = bias[col];
            #pragma unroll
            for (int r = 0; r < 4; ++r) {
                const int row = bm + wm + i * 16 + quad * 4 + r;
                C[(size_t)row * N + col] = acc[i][j][r] + bval;
            }
        }
    }
}

// ---------------- chunked parallel linear scan -------------------------------
// s_t = a_t*s_{t-1} + c_t with a = 1 - b*pk^2, c = b*v*pk.
constexpr int NCHUNK = 64;
constexpr int CLEN   = SEQ / NCHUNK;     // 32
constexpr int NGH    = BATCH * HEADS * HD;  // 4096 independent lanes

__global__ __launch_bounds__(256) void scan_phase1(const unsigned short* __restrict__ pk_,
                                                   const unsigned short* __restrict__ v_,
                                                   const float* __restrict__ b_,
                                                   float* __restrict__ Aarr,
                                                   float* __restrict__ Carr)
{
    const int idx   = blockIdx.x * 256 + threadIdx.x;   // 0 .. NGH*NCHUNK-1
    const int d     = idx & 63;
    const int h     = (idx >> 6) & 15;
    const int bb    = (idx >> 10) & 3;
    const int chunk = idx >> 12;
    const int g     = idx & (NGH - 1);
    const int t0    = chunk * CLEN;

    const unsigned short* pkp = pk_ + (size_t)bb * SEQ * H_DIM + h * HD + d + (size_t)t0 * H_DIM;
    const unsigned short* vp  = v_  + (size_t)bb * SEQ * H_DIM + h * HD + d + (size_t)t0 * H_DIM;
    const float*          bp  = b_  + (size_t)bb * SEQ * HEADS + h        + (size_t)t0 * HEADS;

    float A = 1.f, C = 0.f;
    #pragma unroll 8
    for (int t = 0; t < CLEN; ++t) {
        float pk = bf2f(pkp[(size_t)t * H_DIM]);
        float vv = bf2f(vp[(size_t)t * H_DIM]);
        float bt = bp[(size_t)t * HEADS];
        float a  = 1.f - bt * pk * pk;
        float c  = bt * vv * pk;
        A *= a;
        C = fmaf(a, C, c);
    }
    Aarr[(size_t)chunk * NGH + g] = A;
    Carr[(size_t)chunk * NGH + g] = C;
}

__global__ __launch_bounds__(256) void scan_phase2(const float* __restrict__ Aarr,
                                                   const float* __restrict__ Carr,
                                                   float* __restrict__ S0)
{
    const int g = blockIdx.x * 256 + threadIdx.x;   // 0..4095
    float s = 0.f;
    #pragma unroll
    for (int c = 0; c < NCHUNK; ++c) {
        S0[(size_t)c * NGH + g] = s;
        s = fmaf(Aarr[(size_t)c * NGH + g], s, Carr[(size_t)c * NGH + g]);
    }
}

__global__ __launch_bounds__(256) void scan_phase3(const unsigned short* __restrict__ pk_,
                                                   unsigned short* __restrict__ pq_,   // in: phi_q, out: ys
                                                   const unsigned short* __restrict__ v_,
                                                   const float* __restrict__ b_,
                                                   const float* __restrict__ S0)
{
    const int idx   = blockIdx.x * 256 + threadIdx.x;
    const int d     = idx & 63;
    const int h     = (idx >> 6) & 15;
    const int bb    = (idx >> 10) & 3;
    const int chunk = idx >> 12;
    const int g     = idx & (NGH - 1);
    const int t0    = chunk * CLEN;

    const unsigned short* pkp = pk_ + (size_t)bb * SEQ * H_DIM + h * HD + d + (size_t)t0 * H_DIM;
    unsigned short*       pqp = pq_ + (size_t)bb * SEQ * H_DIM + h * HD + d + (size_t)t0 * H_DIM;
    const unsigned short* vp  = v_  + (size_t)bb * SEQ * H_DIM + h * HD + d + (size_t)t0 * H_DIM;
    const float*          bp  = b_  + (size_t)bb * SEQ * HEADS + h        + (size_t)t0 * HEADS;

    float s = S0[(size_t)chunk * NGH + g];
    #pragma unroll 8
    for (int t = 0; t < CLEN; ++t) {
        float pk = bf2f(pkp[(size_t)t * H_DIM]);
        float pq = bf2f(pqp[(size_t)t * H_DIM]);
        float vv = bf2f(vp[(size_t)t * H_DIM]);
        float bt = bp[(size_t)t * HEADS];
        float bdv = bt * (vv - s * pk);   // identical op order to the sequential version
        s = fmaf(bdv, pk, s);
        pqp[(size_t)t * H_DIM] = f2bf(s * pq);
    }
}

extern "C" void kernel_launch(void* const* d_in, const int* in_sizes, int n_in,
                              void* d_out, int out_size, void* d_ws, size_t ws_size,
                              hipStream_t stream)
{
    const float* query = (const float*)d_in[0];
    const float* key   = (const float*)d_in[1];
    const float* value = (const float*)d_in[2];
    const float* beta  = (const float*)d_in[3];
    const float* Wq    = (const float*)d_in[4];
    const float* bq    = (const float*)d_in[5];
    const float* Wk    = (const float*)d_in[6];
    const float* bk    = (const float*)d_in[7];
    const float* Wv    = (const float*)d_in[8];
    const float* bv    = (const float*)d_in[9];
    const float* Wb    = (const float*)d_in[10];
    const float* bbias = (const float*)d_in[11];
    const float* Wo    = (const float*)d_in[12];
    const float* bo    = (const float*)d_in[13];
    float* out = (float*)d_out;

    const size_t ACT = (size_t)M_ROWS * H_DIM;   // 8 Mi elems
    const size_t WEL = (size_t)H_DIM * H_DIM;    // 1 Mi elems

    unsigned short* ws = (unsigned short*)d_ws;
    unsigned short* Xq     = ws;                 // bf16 staging, query
    unsigned short* phi_q  = ws + ACT;           // bf16 [8192,1024]; ys written in-place
    unsigned short* phi_k  = ws + 2 * ACT;
    unsigned short* vbuf   = ws + 3 * ACT;
    unsigned short* Wq_bf  = ws + 4 * ACT;
    unsigned short* Wk_bf  = Wq_bf + WEL;
    unsigned short* Wv_bf  = Wk_bf + WEL;
    unsigned short* Wo_bf  = Wv_bf + WEL;
    float*          bbuf   = (float*)(Wo_bf + WEL);        // [8192,16]
    float*          Aarr   = bbuf + (size_t)M_ROWS * HEADS; // [64][4096]
    float*          Carr   = Aarr + (size_t)NCHUNK * NGH;
    float*          S0     = Carr + (size_t)NCHUNK * NGH;

    // d_out (8192x1024 f32 = 33.5 MB) doubles as bf16 staging for key/value
    // inputs; dead until gemm_out writes it at the very end.
    unsigned short* Xk = (unsigned short*)d_out;
    unsigned short* Xv = (unsigned short*)d_out + ACT;

    const int ACT_CAST_BLOCKS = (int)(ACT / (8 * 256));   // 4096

    // 1) weight casts + proj_b in one launch
    prep<<<dim3(2048, 1, 5), 256, 0, stream>>>(Wq, Wk, Wv, Wo,
                                               Wq_bf, Wk_bf, Wv_bf, Wo_bf,
                                               beta, Wb, bbias, bbuf);

    // 2) activation casts (q,k,v) in one launch
    cast_bf16_z<<<dim3(ACT_CAST_BLOCKS, 1, 3), 256, 0, stream>>>(
        query, key, value, Xq, Xk, Xv);

    // 3) QKV projections: bf16 A via global_load_lds, XCD-swizzled 1-D grid
    gemm_qkv<<<1536, 256, 0, stream>>>(Xq, Xk, Xv,
                                       Wq_bf, Wk_bf, Wv_bf,
                                       bq, bk, bv,
                                       phi_q, phi_k, vbuf);

    // 4-6) chunked scan
    const int SCAN_BLOCKS = NGH * NCHUNK / 256;   // 1024
    scan_phase1<<<SCAN_BLOCKS, 256, 0, stream>>>(phi_k, vbuf, bbuf, Aarr, Carr);
    scan_phase2<<<NGH / 256, 256, 0, stream>>>(Aarr, Carr, S0);
    scan_phase3<<<SCAN_BLOCKS, 256, 0, stream>>>(phi_k, phi_q, vbuf, bbuf, S0);

    // 7) output projection, 128x64 tile -> 1024 blocks (4/CU), XCD-swizzled
    gemm_out<<<1024, 256, 0, stream>>>(phi_q, Wo_bf, bo, out);
}

// Round 4
// 332.778 us; speedup vs baseline: 1.0970x; 1.0150x over previous
//
#include <hip/hip_runtime.h>
#include <cstdint>
#include <cstddef>

#define H_DIM 1024
#define HEADS 16
#define HD 64
#define BATCH 4
#define SEQ 2048
#define M_ROWS (BATCH*SEQ)   // 8192

typedef __bf16 bf16x8 __attribute__((ext_vector_type(8)));
typedef float floatx4 __attribute__((ext_vector_type(4)));
typedef unsigned short ushortx8 __attribute__((ext_vector_type(8)));

__device__ __forceinline__ unsigned short f2bf(float f) {
    union { float f; uint32_t u; } c; c.f = f;
    uint32_t u = c.u;
    u += 0x7fffu + ((u >> 16) & 1u);     // RNE
    return (unsigned short)(u >> 16);
}
__device__ __forceinline__ float bf2f(unsigned short h) {
    union { uint32_t u; float f; } c; c.u = ((uint32_t)h) << 16;
    return c.f;
}

// async global->LDS, 16B per lane; LDS dest = wave-uniform base + lane*16 (m104/m108)
#define GLD_LDS16(gp, lp) \
    __builtin_amdgcn_global_load_lds((__attribute__((address_space(1))) void*)(gp), \
                                     (__attribute__((address_space(3))) void*)(lp), 16, 0, 0)

// ---------------- prep: 4 weight casts (z<4) + proj_b (z==4) in one launch ----
// grid (2048, 1, 5). z<4: blocks >=512 exit immediately.
__global__ __launch_bounds__(256) void prep(const float* __restrict__ Wq,
                                            const float* __restrict__ Wk,
                                            const float* __restrict__ Wv,
                                            const float* __restrict__ Wo,
                                            unsigned short* __restrict__ Wq_bf,
                                            unsigned short* __restrict__ Wk_bf,
                                            unsigned short* __restrict__ Wv_bf,
                                            unsigned short* __restrict__ Wo_bf,
                                            const float* __restrict__ beta,
                                            const float* __restrict__ Wb,
                                            const float* __restrict__ bbias,
                                            float* __restrict__ bout)
{
    const int z = blockIdx.z;
    if (z < 4) {
        if (blockIdx.x >= 512) return;
        const float* in = (z == 0) ? Wq : (z == 1) ? Wk : (z == 2) ? Wv : Wo;
        unsigned short* out = (z == 0) ? Wq_bf : (z == 1) ? Wk_bf : (z == 2) ? Wv_bf : Wo_bf;
        size_t i = (size_t)blockIdx.x * 256 + threadIdx.x;
        const float4* p = (const float4*)in;
        float4 a = p[i * 2], b = p[i * 2 + 1];
        ushortx8 o;
        o[0] = f2bf(a.x); o[1] = f2bf(a.y); o[2] = f2bf(a.z); o[3] = f2bf(a.w);
        o[4] = f2bf(b.x); o[5] = f2bf(b.y); o[6] = f2bf(b.z); o[7] = f2bf(b.w);
        *(ushortx8*)(out + i * 8) = o;
        return;
    }

    // ---- proj_b: b = sigmoid(beta @ Wb^T + bb), wave-per-row, coalesced ----
    const int wave = threadIdx.x >> 6;
    const int lane = threadIdx.x & 63;
    const int m = blockIdx.x * 4 + wave;

    const float4* brow = (const float4*)(beta + (size_t)m * H_DIM);   // 256 float4
    const float4* wb4  = (const float4*)Wb;                            // [16][256] float4

    float acc[16];
    #pragma unroll
    for (int n = 0; n < 16; ++n) acc[n] = 0.f;

    #pragma unroll
    for (int j = 0; j < 4; ++j) {
        float4 a = brow[j * 64 + lane];            // 1KB coalesced
        #pragma unroll
        for (int n = 0; n < 16; ++n) {
            float4 w = wb4[n * 256 + j * 64 + lane];   // 1KB coalesced, L1/L2-hot
            acc[n] = fmaf(a.x, w.x, acc[n]);
            acc[n] = fmaf(a.y, w.y, acc[n]);
            acc[n] = fmaf(a.z, w.z, acc[n]);
            acc[n] = fmaf(a.w, w.w, acc[n]);
        }
    }

    #pragma unroll
    for (int n = 0; n < 16; ++n) {
        float s = acc[n];
        s += __shfl_xor(s, 32);
        s += __shfl_xor(s, 16);
        s += __shfl_xor(s, 8);
        s += __shfl_xor(s, 4);
        s += __shfl_xor(s, 2);
        s += __shfl_xor(s, 1);
        acc[n] = s;
    }

    float sel = acc[0];
    #pragma unroll
    for (int n = 1; n < 16; ++n)
        sel = (lane == n) ? acc[n] : sel;
    if (lane < 16) {
        float s = sel + bbias[lane];
        bout[(size_t)m * HEADS + lane] = 1.f / (1.f + __expf(-s));
    }
}

// ---------------- z-batched activation f32 -> bf16 cast (8 elems/thread) -----
__global__ __launch_bounds__(256) void cast_bf16_z(const float* __restrict__ p0,
                                                   const float* __restrict__ p1,
                                                   const float* __restrict__ p2,
                                                   unsigned short* __restrict__ o0,
                                                   unsigned short* __restrict__ o1,
                                                   unsigned short* __restrict__ o2)
{
    const int z = blockIdx.z;
    const float* in = (z == 0) ? p0 : (z == 1) ? p1 : p2;
    unsigned short* out = (z == 0) ? o0 : (z == 1) ? o1 : o2;

    size_t i = (size_t)blockIdx.x * 256 + threadIdx.x;
    const float4* p = (const float4*)in;
    float4 a = p[i * 2], b = p[i * 2 + 1];
    ushortx8 o;
    o[0] = f2bf(a.x); o[1] = f2bf(a.y); o[2] = f2bf(a.z); o[3] = f2bf(a.w);
    o[4] = f2bf(b.x); o[5] = f2bf(b.y); o[6] = f2bf(b.z); o[7] = f2bf(b.w);
    *(ushortx8*)(out + i * 8) = o;
}

// ---------------- QKV GEMM: bf16 A via global_load_lds, ----------------------
// 1-D grid 1536 with panel-per-XCD swizzle: each A-panel's 8 N-blocks land on
// one XCD -> A-panel L2-fetched ~once (fetch 200->43 MB measured r2/r3).
__global__ __launch_bounds__(256) void gemm_qkv(const unsigned short* __restrict__ Aq,
                                                const unsigned short* __restrict__ Ak,
                                                const unsigned short* __restrict__ Av,
                                                const unsigned short* __restrict__ Wqb,
                                                const unsigned short* __restrict__ Wkb,
                                                const unsigned short* __restrict__ Wvb,
                                                const float* __restrict__ bq,
                                                const float* __restrict__ bk,
                                                const float* __restrict__ bv,
                                                unsigned short* __restrict__ Cq,
                                                unsigned short* __restrict__ Ck,
                                                unsigned short* __restrict__ Cv)
{
    constexpr int TM = 128, TN = 128, TK = 32;
    constexpr int K = H_DIM, N = H_DIM;
    __shared__ __align__(16) unsigned short Ast[TM * TK];
    __shared__ __align__(16) unsigned short Bst[TN * TK];

    // swizzle decode: lin -> (z, my, nx); panels = 64 M-tiles x 3 z = 192
    const int lin   = blockIdx.x;          // 0..1535
    const int xcd   = lin & 7;
    const int ii    = lin >> 3;            // 0..191 (per-XCD index)
    const int panel = xcd * 24 + (ii >> 3);
    const int nx    = ii & 7;
    const int z     = panel >> 6;          // 0..2
    const int my    = panel & 63;

    const unsigned short* A = (z == 0) ? Aq : (z == 1) ? Ak : Av;
    const unsigned short* W = (z == 0) ? Wqb : (z == 1) ? Wkb : Wvb;
    const float* bias       = (z == 0) ? bq : (z == 1) ? bk : bv;
    unsigned short* C       = (z == 0) ? Cq : (z == 1) ? Ck : Cv;
    const bool phi = (z < 2);

    const int tid  = threadIdx.x;
    const int wave = tid >> 6;
    const int lane = tid & 63;
    const int bm = my * TM;
    const int bn = nx * TN;

    const int srow  = wave * 16 + (lane >> 2);
    const int skoff = (lane & 3) * 8;

    const int wm   = (wave & 1) * 64;
    const int wn   = (wave >> 1) * 64;
    const int quad = lane >> 4;
    const int l16  = lane & 15;

    floatx4 acc[4][4] = {};

    const unsigned short* Abase = A + (size_t)bm * K;
    const unsigned short* Wbase = W + (size_t)bn * K;

    for (int k0 = 0; k0 < K; k0 += TK) {
        __syncthreads();
        GLD_LDS16(Abase + (size_t)srow        * K + k0 + skoff, &Ast[(wave * 16)      * TK]);
        GLD_LDS16(Abase + (size_t)(srow + 64) * K + k0 + skoff, &Ast[(64 + wave * 16) * TK]);
        GLD_LDS16(Wbase + (size_t)srow        * K + k0 + skoff, &Bst[(wave * 16)      * TK]);
        GLD_LDS16(Wbase + (size_t)(srow + 64) * K + k0 + skoff, &Bst[(64 + wave * 16) * TK]);
        __syncthreads();

        bf16x8 af[4], bfr[4];
        #pragma unroll
        for (int i = 0; i < 4; ++i)
            af[i] = *(const bf16x8*)&Ast[(wm + i * 16 + l16) * TK + quad * 8];
        #pragma unroll
        for (int j = 0; j < 4; ++j)
            bfr[j] = *(const bf16x8*)&Bst[(wn + j * 16 + l16) * TK + quad * 8];
        #pragma unroll
        for (int i = 0; i < 4; ++i)
            #pragma unroll
            for (int j = 0; j < 4; ++j)
                acc[i][j] = __builtin_amdgcn_mfma_f32_16x16x32_bf16(af[i], bfr[j], acc[i][j], 0, 0, 0);
    }

    #pragma unroll
    for (int i = 0; i < 4; ++i) {
        #pragma unroll
        for (int j = 0; j < 4; ++j) {
            const int col = bn + wn + j * 16 + l16;
            const float bval = bias[col];
            #pragma unroll
            for (int r = 0; r < 4; ++r) {
                const int row = bm + wm + i * 16 + quad * 4 + r;
                float x = acc[i][j][r] + bval;
                if (phi) x = (x > 0.f) ? (x + 1.f) : __expf(x);  // elu(x)+1
                C[(size_t)row * N + col] = f2bf(x);
            }
        }
    }
}

// ---------------- output GEMM: 128x64 tile -> 1024 blocks = 4/CU -------------
__global__ __launch_bounds__(256) void gemm_out(const unsigned short* __restrict__ A,
                                                const unsigned short* __restrict__ W,
                                                const float* __restrict__ bias,
                                                float* __restrict__ C)
{
    constexpr int TM = 128, TN = 64, TK = 32;
    constexpr int K = H_DIM, N = H_DIM;
    __shared__ __align__(16) unsigned short Ast[TM * TK];
    __shared__ __align__(16) unsigned short Bst[TN * TK];

    const int lin = blockIdx.x;           // 0..1023
    const int xcd = lin & 7;
    const int ii  = lin >> 3;             // 0..127
    const int my  = xcd * 8 + (ii >> 4);  // 0..63
    const int nx  = ii & 15;              // 0..15

    const int tid  = threadIdx.x;
    const int wave = tid >> 6;
    const int lane = tid & 63;
    const int bm = my * TM;
    const int bn = nx * TN;

    const int srow  = wave * 16 + (lane >> 2);
    const int skoff = (lane & 3) * 8;

    const int wm   = (wave & 1) * 64;
    const int wn   = (wave >> 1) * 32;
    const int quad = lane >> 4;
    const int l16  = lane & 15;

    floatx4 acc[4][2] = {};

    const unsigned short* Abase = A + (size_t)bm * K;
    const unsigned short* Wbase = W + (size_t)bn * K;

    for (int k0 = 0; k0 < K; k0 += TK) {
        __syncthreads();
        GLD_LDS16(Abase + (size_t)srow        * K + k0 + skoff, &Ast[(wave * 16)      * TK]);
        GLD_LDS16(Abase + (size_t)(srow + 64) * K + k0 + skoff, &Ast[(64 + wave * 16) * TK]);
        GLD_LDS16(Wbase + (size_t)srow        * K + k0 + skoff, &Bst[(wave * 16)      * TK]);
        __syncthreads();

        bf16x8 af[4], bfr[2];
        #pragma unroll
        for (int i = 0; i < 4; ++i)
            af[i] = *(const bf16x8*)&Ast[(wm + i * 16 + l16) * TK + quad * 8];
        #pragma unroll
        for (int j = 0; j < 2; ++j)
            bfr[j] = *(const bf16x8*)&Bst[(wn + j * 16 + l16) * TK + quad * 8];
        #pragma unroll
        for (int i = 0; i < 4; ++i)
            #pragma unroll
            for (int j = 0; j < 2; ++j)
                acc[i][j] = __builtin_amdgcn_mfma_f32_16x16x32_bf16(af[i], bfr[j], acc[i][j], 0, 0, 0);
    }

    #pragma unroll
    for (int i = 0; i < 4; ++i) {
        #pragma unroll
        for (int j = 0; j < 2; ++j) {
            const int col = bn + wn + j * 16 + l16;
            const float bval = bias[col];
            #pragma unroll
            for (int r = 0; r < 4; ++r) {
                const int row = bm + wm + i * 16 + quad * 4 + r;
                C[(size_t)row * N + col] = acc[i][j][r] + bval;
            }
        }
    }
}

// ---------------- chunked parallel linear scan, d-vectorized x8 --------------
// s_t = a_t*s_{t-1} + c_t with a = 1 - b*pk^2, c = b*v*pk.
// Each thread owns 8 consecutive d-channels of one (b,h,chunk): all bf16
// loads/stores are 16B/lane and wave-contiguous (lane l covers elems [8l,8l+8)
// of a 512-elem row). 8 independent recurrence chains/thread = ILP. G13 fix.
constexpr int NCHUNK = 128;
constexpr int CLEN   = SEQ / NCHUNK;        // 16
constexpr int NGH    = BATCH * HEADS * HD;  // 4096 recurrence lanes
constexpr int NG8    = NGH / 8;             // 512 thread-groups per chunk

__global__ __launch_bounds__(256) void scan_phase1(const unsigned short* __restrict__ pk_,
                                                   const unsigned short* __restrict__ v_,
                                                   const float* __restrict__ b_,
                                                   float* __restrict__ Aarr,
                                                   float* __restrict__ Carr)
{
    const int idx   = blockIdx.x * 256 + threadIdx.x;   // 0 .. NG8*NCHUNK-1
    const int gx    = idx & (NG8 - 1);      // (bb,h,d8)
    const int chunk = idx >> 9;             // 0..127
    const int d0    = (gx & 7) * 8;
    const int h     = (gx >> 3) & 15;
    const int bb    = gx >> 7;
    const int g0    = gx * 8;               // first of 8 consecutive g
    const int t0    = chunk * CLEN;

    const size_t base = (size_t)bb * SEQ * H_DIM + (size_t)t0 * H_DIM + h * HD + d0;
    const ushortx8* pk8 = (const ushortx8*)(pk_ + base);   // stride H_DIM/8 per t
    const ushortx8* v8  = (const ushortx8*)(v_  + base);
    const float*    bp  = b_ + (size_t)bb * SEQ * HEADS + (size_t)t0 * HEADS + h;

    float A[8], C[8];
    #pragma unroll
    for (int e = 0; e < 8; ++e) { A[e] = 1.f; C[e] = 0.f; }

    #pragma unroll 4
    for (int t = 0; t < CLEN; ++t) {
        ushortx8 pkv = pk8[t * (H_DIM / 8)];
        ushortx8 vv  = v8[t * (H_DIM / 8)];
        float bt = bp[t * HEADS];
        #pragma unroll
        for (int e = 0; e < 8; ++e) {
            float pk = bf2f(pkv[e]);
            float vf = bf2f(vv[e]);
            float a  = 1.f - bt * pk * pk;
            float c  = bt * vf * pk;
            A[e] *= a;
            C[e] = fmaf(a, C[e], c);
        }
    }
    float4 a0 = {A[0], A[1], A[2], A[3]}, a1 = {A[4], A[5], A[6], A[7]};
    float4 c0 = {C[0], C[1], C[2], C[3]}, c1 = {C[4], C[5], C[6], C[7]};
    *(float4*)&Aarr[(size_t)chunk * NGH + g0]     = a0;
    *(float4*)&Aarr[(size_t)chunk * NGH + g0 + 4] = a1;
    *(float4*)&Carr[(size_t)chunk * NGH + g0]     = c0;
    *(float4*)&Carr[(size_t)chunk * NGH + g0 + 4] = c1;
}

__global__ __launch_bounds__(256) void scan_phase2(const float* __restrict__ Aarr,
                                                   const float* __restrict__ Carr,
                                                   float* __restrict__ S0)
{
    const int g = blockIdx.x * 256 + threadIdx.x;   // 0..4095
    float s = 0.f;
    #pragma unroll 8
    for (int c = 0; c < NCHUNK; ++c) {
        S0[(size_t)c * NGH + g] = s;
        s = fmaf(Aarr[(size_t)c * NGH + g], s, Carr[(size_t)c * NGH + g]);
    }
}

__global__ __launch_bounds__(256) void scan_phase3(const unsigned short* __restrict__ pk_,
                                                   unsigned short* __restrict__ pq_,   // in: phi_q, out: ys
                                                   const unsigned short* __restrict__ v_,
                                                   const float* __restrict__ b_,
                                                   const float* __restrict__ S0)
{
    const int idx   = blockIdx.x * 256 + threadIdx.x;
    const int gx    = idx & (NG8 - 1);
    const int chunk = idx >> 9;
    const int d0    = (gx & 7) * 8;
    const int h     = (gx >> 3) & 15;
    const int bb    = gx >> 7;
    const int g0    = gx * 8;
    const int t0    = chunk * CLEN;

    const size_t base = (size_t)bb * SEQ * H_DIM + (size_t)t0 * H_DIM + h * HD + d0;
    const ushortx8* pk8 = (const ushortx8*)(pk_ + base);
    ushortx8*       pq8 = (ushortx8*)(pq_ + base);
    const ushortx8* v8  = (const ushortx8*)(v_  + base);
    const float*    bp  = b_ + (size_t)bb * SEQ * HEADS + (size_t)t0 * HEADS + h;

    float s[8];
    float4 s0a = *(const float4*)&S0[(size_t)chunk * NGH + g0];
    float4 s0b = *(const float4*)&S0[(size_t)chunk * NGH + g0 + 4];
    s[0] = s0a.x; s[1] = s0a.y; s[2] = s0a.z; s[3] = s0a.w;
    s[4] = s0b.x; s[5] = s0b.y; s[6] = s0b.z; s[7] = s0b.w;

    #pragma unroll 4
    for (int t = 0; t < CLEN; ++t) {
        ushortx8 pkv = pk8[t * (H_DIM / 8)];
        ushortx8 pqv = pq8[t * (H_DIM / 8)];
        ushortx8 vv  = v8[t * (H_DIM / 8)];
        float bt = bp[t * HEADS];
        ushortx8 o;
        #pragma unroll
        for (int e = 0; e < 8; ++e) {
            float pk = bf2f(pkv[e]);
            float pq = bf2f(pqv[e]);
            float vf = bf2f(vv[e]);
            float bdv = bt * (vf - s[e] * pk);   // identical op order to sequential version
            s[e] = fmaf(bdv, pk, s[e]);
            o[e] = f2bf(s[e] * pq);
        }
        pq8[t * (H_DIM / 8)] = o;
    }
}

extern "C" void kernel_launch(void* const* d_in, const int* in_sizes, int n_in,
                              void* d_out, int out_size, void* d_ws, size_t ws_size,
                              hipStream_t stream)
{
    const float* query = (const float*)d_in[0];
    const float* key   = (const float*)d_in[1];
    const float* value = (const float*)d_in[2];
    const float* beta  = (const float*)d_in[3];
    const float* Wq    = (const float*)d_in[4];
    const float* bq    = (const float*)d_in[5];
    const float* Wk    = (const float*)d_in[6];
    const float* bk    = (const float*)d_in[7];
    const float* Wv    = (const float*)d_in[8];
    const float* bv    = (const float*)d_in[9];
    const float* Wb    = (const float*)d_in[10];
    const float* bbias = (const float*)d_in[11];
    const float* Wo    = (const float*)d_in[12];
    const float* bo    = (const float*)d_in[13];
    float* out = (float*)d_out;

    const size_t ACT = (size_t)M_ROWS * H_DIM;   // 8 Mi elems
    const size_t WEL = (size_t)H_DIM * H_DIM;    // 1 Mi elems

    unsigned short* ws = (unsigned short*)d_ws;
    unsigned short* Xq     = ws;                 // bf16 staging, query
    unsigned short* phi_q  = ws + ACT;           // bf16 [8192,1024]; ys written in-place
    unsigned short* phi_k  = ws + 2 * ACT;
    unsigned short* vbuf   = ws + 3 * ACT;
    unsigned short* Wq_bf  = ws + 4 * ACT;
    unsigned short* Wk_bf  = Wq_bf + WEL;
    unsigned short* Wv_bf  = Wk_bf + WEL;
    unsigned short* Wo_bf  = Wv_bf + WEL;
    float*          bbuf   = (float*)(Wo_bf + WEL);        // [8192,16]
    float*          Aarr   = bbuf + (size_t)M_ROWS * HEADS; // [128][4096]
    float*          Carr   = Aarr + (size_t)NCHUNK * NGH;
    float*          S0     = Carr + (size_t)NCHUNK * NGH;

    // d_out (8192x1024 f32 = 33.5 MB) doubles as bf16 staging for key/value
    // inputs; dead until gemm_out writes it at the very end.
    unsigned short* Xk = (unsigned short*)d_out;
    unsigned short* Xv = (unsigned short*)d_out + ACT;

    const int ACT_CAST_BLOCKS = (int)(ACT / (8 * 256));   // 4096

    // 1) weight casts + proj_b in one launch
    prep<<<dim3(2048, 1, 5), 256, 0, stream>>>(Wq, Wk, Wv, Wo,
                                               Wq_bf, Wk_bf, Wv_bf, Wo_bf,
                                               beta, Wb, bbias, bbuf);

    // 2) activation casts (q,k,v) in one launch
    cast_bf16_z<<<dim3(ACT_CAST_BLOCKS, 1, 3), 256, 0, stream>>>(
        query, key, value, Xq, Xk, Xv);

    // 3) QKV projections: bf16 A via global_load_lds, XCD-swizzled 1-D grid
    gemm_qkv<<<1536, 256, 0, stream>>>(Xq, Xk, Xv,
                                       Wq_bf, Wk_bf, Wv_bf,
                                       bq, bk, bv,
                                       phi_q, phi_k, vbuf);

    // 4-6) chunked scan, d-vectorized x8
    const int SCAN_BLOCKS = NG8 * NCHUNK / 256;   // 256
    scan_phase1<<<SCAN_BLOCKS, 256, 0, stream>>>(phi_k, vbuf, bbuf, Aarr, Carr);
    scan_phase2<<<NGH / 256, 256, 0, stream>>>(Aarr, Carr, S0);
    scan_phase3<<<SCAN_BLOCKS, 256, 0, stream>>>(phi_k, phi_q, vbuf, bbuf, S0);

    // 7) output projection, 128x64 tile -> 1024 blocks (4/CU), XCD-swizzled
    gemm_out<<<1024, 256, 0, stream>>>(phi_q, Wo_bf, bo, out);
}